// Round 1
// baseline (967.752 us; speedup 1.0000x reference)
//
#include <hip/hip_runtime.h>

#define N_NODES 50000
#define N_EDGES 800000
#define DIM 128
#define NGRAPH 512
#define ODIM 64

// ---------------------------------------------------------------- embedding
__global__ __launch_bounds__(256) void embed_kernel(
    const float* __restrict__ emb, const int* __restrict__ idx,
    float* __restrict__ x0) {
  int i = blockIdx.x * 256 + threadIdx.x;       // one float4 per thread
  if (i >= N_NODES * 32) return;                // 128 floats = 32 float4 per node
  int n = i >> 5;
  int c = i & 31;
  int v = idx[n];
  const float4* src = (const float4*)(emb + (size_t)v * DIM);
  float4* dst = (float4*)(x0 + (size_t)n * DIM);
  dst[c] = src[c];
}

// ---------------------------------------------------------------- edge aggregation (atomic)
__global__ __launch_bounds__(256) void agg_kernel(
    const float* __restrict__ x, const int* __restrict__ ei,
    float* __restrict__ agg) {
  int e = blockIdx.x * 2 + (threadIdx.x >> 7);
  if (e >= N_EDGES) return;
  int t = threadIdx.x & 127;
  int s = ei[e];
  int d = ei[N_EDGES + e];
  atomicAdd(&agg[(size_t)d * DIM + t], x[(size_t)s * DIM + t]);
}

// ---------------------------------------------------------------- fused 2-layer MLP
// xout = relu( relu((xin+agg) @ Wa^T + ba) @ Wb^T + bb )
// block: 256 threads, 32 nodes. W staged in LDS 32 rows at a time (4 quarters).
#define TN 32
#define WP 132   // pitch in floats: 132%32=4 -> conflict-free strided rows, 528B is 16B-aligned
__global__ __launch_bounds__(256) void mlp_kernel(
    const float* __restrict__ xin, const float* __restrict__ agg,
    const float* __restrict__ wa, const float* __restrict__ ba,
    const float* __restrict__ wb, const float* __restrict__ bb,
    float* __restrict__ xout) {
  __shared__ float Ws[32 * WP];   // 16,896 B  (one 32-row quarter of W)
  __shared__ float Xs[TN * WP];   // 16,896 B
  __shared__ float Hs[TN * WP];   // 16,896 B
  int t = threadIdx.x;
  int base = blockIdx.x * TN;

  // stage X = xin + agg   (1024 float4, 4 per thread)
  for (int i = 0; i < 4; ++i) {
    int idx = i * 256 + t;
    int n = idx >> 5, c = idx & 31;
    float4 v = make_float4(0.f, 0.f, 0.f, 0.f);
    if (base + n < N_NODES) {
      float4 a = ((const float4*)(xin + (size_t)(base + n) * DIM))[c];
      float4 b = ((const float4*)(agg + (size_t)(base + n) * DIM))[c];
      v = make_float4(a.x + b.x, a.y + b.y, a.z + b.z, a.w + b.w);
    }
    *(float4*)&Xs[n * WP + c * 4] = v;
  }

  int n = t >> 3, jl = t & 7;

  // ---- phase 1: Hs = relu(Xs @ Wa^T + ba), by j-quarters of 32
  for (int q = 0; q < 4; ++q) {
    __syncthreads();
    for (int i = 0; i < 4; ++i) {            // stage 32 rows of Wa
      int idx = i * 256 + t;
      int r = idx >> 5, c = idx & 31;
      *(float4*)&Ws[r * WP + c * 4] = ((const float4*)wa)[q * 1024 + idx];
    }
    __syncthreads();
    float acc[4];
    #pragma unroll
    for (int k = 0; k < 4; ++k) acc[k] = ba[q * 32 + jl + 8 * k];
    #pragma unroll 8
    for (int dc = 0; dc < 32; ++dc) {
      float4 xv = *(const float4*)&Xs[n * WP + dc * 4];
      #pragma unroll
      for (int k = 0; k < 4; ++k) {
        float4 wv = *(const float4*)&Ws[(jl + 8 * k) * WP + dc * 4];
        acc[k] += xv.x * wv.x + xv.y * wv.y + xv.z * wv.z + xv.w * wv.w;
      }
    }
    #pragma unroll
    for (int k = 0; k < 4; ++k)
      Hs[n * WP + q * 32 + jl + 8 * k] = fmaxf(acc[k], 0.0f);
  }

  // ---- phase 2: Xs = relu(Hs @ Wb^T + bb)  (reuse Xs as output staging)
  for (int q = 0; q < 4; ++q) {
    __syncthreads();
    for (int i = 0; i < 4; ++i) {            // stage 32 rows of Wb
      int idx = i * 256 + t;
      int r = idx >> 5, c = idx & 31;
      *(float4*)&Ws[r * WP + c * 4] = ((const float4*)wb)[q * 1024 + idx];
    }
    __syncthreads();
    float acc[4];
    #pragma unroll
    for (int k = 0; k < 4; ++k) acc[k] = bb[q * 32 + jl + 8 * k];
    #pragma unroll 8
    for (int dc = 0; dc < 32; ++dc) {
      float4 hv = *(const float4*)&Hs[n * WP + dc * 4];
      #pragma unroll
      for (int k = 0; k < 4; ++k) {
        float4 wv = *(const float4*)&Ws[(jl + 8 * k) * WP + dc * 4];
        acc[k] += hv.x * wv.x + hv.y * wv.y + hv.z * wv.z + hv.w * wv.w;
      }
    }
    // Xs reads finished before first phase-2 barrier; safe to overwrite
    #pragma unroll
    for (int k = 0; k < 4; ++k)
      Xs[n * WP + q * 32 + jl + 8 * k] = fmaxf(acc[k], 0.0f);
  }
  __syncthreads();

  // write out (coalesced float4)
  for (int i = 0; i < 4; ++i) {
    int idx = i * 256 + t;
    int nn = idx >> 5, c = idx & 31;
    if (base + nn < N_NODES)
      *(float4*)&xout[(size_t)(base + nn) * DIM + c * 4] =
          *(const float4*)&Xs[nn * WP + c * 4];
  }
}

// ---------------------------------------------------------------- mean-pool (sorted batch) + FC
__global__ __launch_bounds__(128) void pool_fc_kernel(
    const float* __restrict__ x, const int* __restrict__ batch,
    const float* __restrict__ fcw, const float* __restrict__ fcb,
    float* __restrict__ out) {
  int g = blockIdx.x, t = threadIdx.x;
  __shared__ float pooled[DIM];
  __shared__ int sbound[2];
  if (t < 2) {
    int target = g + t;          // lower_bound(batch, target)
    int lo = 0, hi = N_NODES;
    while (lo < hi) {
      int m = (lo + hi) >> 1;
      if (batch[m] < target) lo = m + 1; else hi = m;
    }
    sbound[t] = lo;
  }
  __syncthreads();
  int lo = sbound[0], hi = sbound[1];
  float s = 0.f;
  for (int nn = lo; nn < hi; ++nn) s += x[(size_t)nn * DIM + t];
  pooled[t] = s / fmaxf((float)(hi - lo), 1.0f);
  __syncthreads();
  if (t < ODIM) {
    float a = fcb[t];
    const float* wr = fcw + (size_t)t * DIM;
    #pragma unroll 8
    for (int h = 0; h < DIM; ++h) a += pooled[h] * wr[h];
    out[(size_t)g * ODIM + t] = a;
  }
}

// ---------------------------------------------------------------- launch
extern "C" void kernel_launch(void* const* d_in, const int* in_sizes, int n_in,
                              void* d_out, int out_size, void* d_ws, size_t ws_size,
                              hipStream_t stream) {
  const float* emb  = (const float*)d_in[0];
  const float* w1a  = (const float*)d_in[1];
  const float* b1a  = (const float*)d_in[2];
  const float* w1b  = (const float*)d_in[3];
  const float* b1b  = (const float*)d_in[4];
  const float* w2a  = (const float*)d_in[5];
  const float* b2a  = (const float*)d_in[6];
  const float* w2b  = (const float*)d_in[7];
  const float* b2b  = (const float*)d_in[8];
  const float* fcw  = (const float*)d_in[9];
  const float* fcb  = (const float*)d_in[10];
  const int*   xidx = (const int*)d_in[11];
  const int*   ei   = (const int*)d_in[12];
  const int*   batch= (const int*)d_in[13];
  float* out = (float*)d_out;

  size_t feat_bytes = (size_t)N_NODES * DIM * sizeof(float);   // 25.6 MB
  char* ws = (char*)d_ws;
  float* A = (float*)ws;                       // x0 / x2
  float* B = (float*)(ws + feat_bytes);        // agg
  float* C = (float*)(ws + 2 * feat_bytes);    // x1

  embed_kernel<<<(N_NODES * 32 + 255) / 256, 256, 0, stream>>>(emb, xidx, A);

  hipMemsetAsync(B, 0, feat_bytes, stream);
  agg_kernel<<<(N_EDGES + 1) / 2, 256, 0, stream>>>(A, ei, B);
  mlp_kernel<<<(N_NODES + TN - 1) / TN, 256, 0, stream>>>(A, B, w1a, b1a, w1b, b1b, C);

  hipMemsetAsync(B, 0, feat_bytes, stream);
  agg_kernel<<<(N_EDGES + 1) / 2, 256, 0, stream>>>(C, ei, B);
  mlp_kernel<<<(N_NODES + TN - 1) / TN, 256, 0, stream>>>(C, B, w2a, b2a, w2b, b2b, A);

  pool_fc_kernel<<<NGRAPH, 128, 0, stream>>>(A, batch, fcw, fcb, out);
}

// Round 2
// 478.655 us; speedup vs baseline: 2.0218x; 2.0218x over previous
//
#include <hip/hip_runtime.h>

#define N_NODES 50000
#define N_EDGES 800000
#define DIM 128
#define NGRAPH 512
#define ODIM 64

// ---------------------------------------------------------------- embedding
__global__ __launch_bounds__(256) void embed_kernel(
    const float* __restrict__ emb, const int* __restrict__ idx,
    float* __restrict__ x0) {
  int i = blockIdx.x * 256 + threadIdx.x;       // one float4 per thread
  if (i >= N_NODES * 32) return;                // 128 floats = 32 float4 per node
  int n = i >> 5;
  int c = i & 31;
  int v = idx[n];
  const float4* src = (const float4*)(emb + (size_t)v * DIM);
  float4* dst = (float4*)(x0 + (size_t)n * DIM);
  dst[c] = src[c];
}

// ---------------------------------------------------------------- CSR build
__global__ __launch_bounds__(256) void hist_kernel(
    const int* __restrict__ ei, int* __restrict__ cnt) {
  int e = blockIdx.x * 256 + threadIdx.x;
  if (e >= N_EDGES) return;
  atomicAdd(&cnt[ei[N_EDGES + e]], 1);
}

// single-block exclusive scan of cnt[0..N_NODES) -> row[0..N_NODES]
#define VPT 8
__global__ __launch_bounds__(1024) void scan_kernel(
    const int* __restrict__ cnt, int* __restrict__ row) {
  __shared__ int wsum[16];
  __shared__ int scarry;
  int t = threadIdx.x;
  int lane = t & 63, wid = t >> 6;
  if (t == 0) scarry = 0;
  __syncthreads();
  for (int base = 0; base < N_NODES; base += 1024 * VPT) {
    int v[VPT];
    int idx0 = base + t * VPT;
    #pragma unroll
    for (int i = 0; i < VPT; ++i) {
      int idx = idx0 + i;
      v[i] = (idx < N_NODES) ? cnt[idx] : 0;
    }
    #pragma unroll
    for (int i = 1; i < VPT; ++i) v[i] += v[i - 1];   // local inclusive
    int tsum = v[VPT - 1];
    int s = tsum;                                      // wave inclusive scan
    #pragma unroll
    for (int d = 1; d < 64; d <<= 1) {
      int u = __shfl_up(s, d, 64);
      if (lane >= d) s += u;
    }
    if (lane == 63) wsum[wid] = s;
    __syncthreads();
    if (wid == 0) {
      int ws = (lane < 16) ? wsum[lane] : 0;
      #pragma unroll
      for (int d = 1; d < 16; d <<= 1) {
        int u = __shfl_up(ws, d, 64);
        if (lane >= d) ws += u;
      }
      if (lane < 16) wsum[lane] = ws;                  // inclusive wave sums
    }
    __syncthreads();
    int wave_excl = (wid == 0) ? 0 : wsum[wid - 1];
    int thread_excl = scarry + wave_excl + (s - tsum);
    if (idx0 < N_NODES) row[idx0] = thread_excl;
    #pragma unroll
    for (int i = 1; i < VPT; ++i) {
      int idx = idx0 + i;
      if (idx < N_NODES) row[idx] = thread_excl + v[i - 1];
    }
    __syncthreads();                 // all reads of scarry/wsum done
    if (t == 0) scarry += wsum[15];
    __syncthreads();
  }
  if (t == 0) row[N_NODES] = scarry; // == N_EDGES
}

__global__ __launch_bounds__(256) void scatter_kernel(
    const int* __restrict__ ei, const int* __restrict__ row,
    int* __restrict__ fill, int* __restrict__ srt_src) {
  int e = blockIdx.x * 256 + threadIdx.x;
  if (e >= N_EDGES) return;
  int s = ei[e];
  int d = ei[N_EDGES + e];
  int pos = row[d] + atomicAdd(&fill[d], 1);
  srt_src[pos] = s;
}

// ---------------------------------------------------------------- CSR aggregation
// 32 lanes per node (float4 per lane), 8 nodes per 256-block. Writes agg once.
__global__ __launch_bounds__(256) void agg_csr_kernel(
    const float* __restrict__ x, const int* __restrict__ row,
    const int* __restrict__ srt, float* __restrict__ agg) {
  int n = blockIdx.x * 8 + (threadIdx.x >> 5);
  int c = threadIdx.x & 31;
  int lo = row[n], hi = row[n + 1];
  const float4* x4 = (const float4*)x;
  float4 acc = make_float4(0.f, 0.f, 0.f, 0.f);
  int k = lo;
  for (; k + 2 <= hi; k += 2) {
    int s0 = srt[k], s1 = srt[k + 1];
    float4 a = x4[(size_t)s0 * 32 + c];
    float4 b = x4[(size_t)s1 * 32 + c];
    acc.x += a.x + b.x; acc.y += a.y + b.y;
    acc.z += a.z + b.z; acc.w += a.w + b.w;
  }
  if (k < hi) {
    float4 a = x4[(size_t)srt[k] * 32 + c];
    acc.x += a.x; acc.y += a.y; acc.z += a.z; acc.w += a.w;
  }
  ((float4*)agg)[(size_t)n * 32 + c] = acc;
}

// ---------------------------------------------------------------- fused 2-layer MLP
// xout = relu( relu((xin+agg) @ Wa^T + ba) @ Wb^T + bb )
#define TN 32
#define WP 132
__global__ __launch_bounds__(256) void mlp_kernel(
    const float* __restrict__ xin, const float* __restrict__ agg,
    const float* __restrict__ wa, const float* __restrict__ ba,
    const float* __restrict__ wb, const float* __restrict__ bb,
    float* __restrict__ xout) {
  __shared__ float Ws[32 * WP];
  __shared__ float Xs[TN * WP];
  __shared__ float Hs[TN * WP];
  int t = threadIdx.x;
  int base = blockIdx.x * TN;

  for (int i = 0; i < 4; ++i) {
    int idx = i * 256 + t;
    int n = idx >> 5, c = idx & 31;
    float4 v = make_float4(0.f, 0.f, 0.f, 0.f);
    if (base + n < N_NODES) {
      float4 a = ((const float4*)(xin + (size_t)(base + n) * DIM))[c];
      float4 b = ((const float4*)(agg + (size_t)(base + n) * DIM))[c];
      v = make_float4(a.x + b.x, a.y + b.y, a.z + b.z, a.w + b.w);
    }
    *(float4*)&Xs[n * WP + c * 4] = v;
  }

  int n = t >> 3, jl = t & 7;

  for (int q = 0; q < 4; ++q) {
    __syncthreads();
    for (int i = 0; i < 4; ++i) {
      int idx = i * 256 + t;
      int r = idx >> 5, c = idx & 31;
      *(float4*)&Ws[r * WP + c * 4] = ((const float4*)wa)[q * 1024 + idx];
    }
    __syncthreads();
    float acc[4];
    #pragma unroll
    for (int k = 0; k < 4; ++k) acc[k] = ba[q * 32 + jl + 8 * k];
    #pragma unroll 8
    for (int dc = 0; dc < 32; ++dc) {
      float4 xv = *(const float4*)&Xs[n * WP + dc * 4];
      #pragma unroll
      for (int k = 0; k < 4; ++k) {
        float4 wv = *(const float4*)&Ws[(jl + 8 * k) * WP + dc * 4];
        acc[k] += xv.x * wv.x + xv.y * wv.y + xv.z * wv.z + xv.w * wv.w;
      }
    }
    #pragma unroll
    for (int k = 0; k < 4; ++k)
      Hs[n * WP + q * 32 + jl + 8 * k] = fmaxf(acc[k], 0.0f);
  }

  for (int q = 0; q < 4; ++q) {
    __syncthreads();
    for (int i = 0; i < 4; ++i) {
      int idx = i * 256 + t;
      int r = idx >> 5, c = idx & 31;
      *(float4*)&Ws[r * WP + c * 4] = ((const float4*)wb)[q * 1024 + idx];
    }
    __syncthreads();
    float acc[4];
    #pragma unroll
    for (int k = 0; k < 4; ++k) acc[k] = bb[q * 32 + jl + 8 * k];
    #pragma unroll 8
    for (int dc = 0; dc < 32; ++dc) {
      float4 hv = *(const float4*)&Hs[n * WP + dc * 4];
      #pragma unroll
      for (int k = 0; k < 4; ++k) {
        float4 wv = *(const float4*)&Ws[(jl + 8 * k) * WP + dc * 4];
        acc[k] += hv.x * wv.x + hv.y * wv.y + hv.z * wv.z + hv.w * wv.w;
      }
    }
    #pragma unroll
    for (int k = 0; k < 4; ++k)
      Xs[n * WP + q * 32 + jl + 8 * k] = fmaxf(acc[k], 0.0f);
  }
  __syncthreads();

  for (int i = 0; i < 4; ++i) {
    int idx = i * 256 + t;
    int nn = idx >> 5, c = idx & 31;
    if (base + nn < N_NODES)
      *(float4*)&xout[(size_t)(base + nn) * DIM + c * 4] =
          *(const float4*)&Xs[nn * WP + c * 4];
  }
}

// ---------------------------------------------------------------- mean-pool + FC
__global__ __launch_bounds__(128) void pool_fc_kernel(
    const float* __restrict__ x, const int* __restrict__ batch,
    const float* __restrict__ fcw, const float* __restrict__ fcb,
    float* __restrict__ out) {
  int g = blockIdx.x, t = threadIdx.x;
  __shared__ float pooled[DIM];
  __shared__ int sbound[2];
  if (t < 2) {
    int target = g + t;
    int lo = 0, hi = N_NODES;
    while (lo < hi) {
      int m = (lo + hi) >> 1;
      if (batch[m] < target) lo = m + 1; else hi = m;
    }
    sbound[t] = lo;
  }
  __syncthreads();
  int lo = sbound[0], hi = sbound[1];
  float s = 0.f;
  for (int nn = lo; nn < hi; ++nn) s += x[(size_t)nn * DIM + t];
  pooled[t] = s / fmaxf((float)(hi - lo), 1.0f);
  __syncthreads();
  if (t < ODIM) {
    float a = fcb[t];
    const float* wr = fcw + (size_t)t * DIM;
    #pragma unroll 8
    for (int h = 0; h < DIM; ++h) a += pooled[h] * wr[h];
    out[(size_t)g * ODIM + t] = a;
  }
}

// ---------------------------------------------------------------- launch
extern "C" void kernel_launch(void* const* d_in, const int* in_sizes, int n_in,
                              void* d_out, int out_size, void* d_ws, size_t ws_size,
                              hipStream_t stream) {
  const float* emb  = (const float*)d_in[0];
  const float* w1a  = (const float*)d_in[1];
  const float* b1a  = (const float*)d_in[2];
  const float* w1b  = (const float*)d_in[3];
  const float* b1b  = (const float*)d_in[4];
  const float* w2a  = (const float*)d_in[5];
  const float* b2a  = (const float*)d_in[6];
  const float* w2b  = (const float*)d_in[7];
  const float* b2b  = (const float*)d_in[8];
  const float* fcw  = (const float*)d_in[9];
  const float* fcb  = (const float*)d_in[10];
  const int*   xidx = (const int*)d_in[11];
  const int*   ei   = (const int*)d_in[12];
  const int*   batch= (const int*)d_in[13];
  float* out = (float*)d_out;

  size_t feat_bytes = (size_t)N_NODES * DIM * sizeof(float);   // 25.6 MB
  char* ws = (char*)d_ws;
  float* A = (float*)ws;                        // x0 / x2
  float* B = (float*)(ws + feat_bytes);         // agg
  float* C = (float*)(ws + 2 * feat_bytes);     // x1
  char*  p = ws + 3 * feat_bytes;
  int* row = (int*)p;                p += ((N_NODES + 1) * 4 + 15) / 16 * 16;
  int* cnt = (int*)p;                p += (N_NODES * 4 + 15) / 16 * 16;   // also 'fill'
  int* srt = (int*)p;                // N_EDGES ints

  embed_kernel<<<(N_NODES * 32 + 255) / 256, 256, 0, stream>>>(emb, xidx, A);

  // CSR build (by dst)
  hipMemsetAsync(cnt, 0, N_NODES * sizeof(int), stream);
  hist_kernel<<<N_EDGES / 256, 256, 0, stream>>>(ei, cnt);
  scan_kernel<<<1, 1024, 0, stream>>>(cnt, row);
  hipMemsetAsync(cnt, 0, N_NODES * sizeof(int), stream);
  scatter_kernel<<<N_EDGES / 256, 256, 0, stream>>>(ei, row, cnt, srt);

  agg_csr_kernel<<<N_NODES / 8, 256, 0, stream>>>(A, row, srt, B);
  mlp_kernel<<<(N_NODES + TN - 1) / TN, 256, 0, stream>>>(A, B, w1a, b1a, w1b, b1b, C);

  agg_csr_kernel<<<N_NODES / 8, 256, 0, stream>>>(C, row, srt, B);
  mlp_kernel<<<(N_NODES + TN - 1) / TN, 256, 0, stream>>>(C, B, w2a, b2a, w2b, b2b, A);

  pool_fc_kernel<<<NGRAPH, 128, 0, stream>>>(A, batch, fcw, fcb, out);
}

// Round 3
// 332.062 us; speedup vs baseline: 2.9144x; 1.4415x over previous
//
#include <hip/hip_runtime.h>

#define N_NODES 50000
#define N_EDGES 800000
#define DIM 128
#define NGRAPH 512
#define ODIM 64

typedef __attribute__((ext_vector_type(8))) short bf16x8;
typedef __attribute__((ext_vector_type(4))) float f32x4;

__device__ inline unsigned short f2bf(float f) {
  unsigned u = __builtin_bit_cast(unsigned, f);
  return (unsigned short)((u + 0x7fffu + ((u >> 16) & 1u)) >> 16);
}

// ---------------------------------------------------------------- embedding
__global__ __launch_bounds__(256) void embed_kernel(
    const float* __restrict__ emb, const int* __restrict__ idx,
    float* __restrict__ x0) {
  int i = blockIdx.x * 256 + threadIdx.x;
  if (i >= N_NODES * 32) return;
  int n = i >> 5;
  int c = i & 31;
  int v = idx[n];
  const float4* src = (const float4*)(emb + (size_t)v * DIM);
  float4* dst = (float4*)(x0 + (size_t)n * DIM);
  dst[c] = src[c];
}

// ---------------------------------------------------------------- CSR build
__global__ __launch_bounds__(256) void hist_kernel(
    const int* __restrict__ ei, int* __restrict__ cnt) {
  int e = blockIdx.x * 256 + threadIdx.x;
  if (e >= N_EDGES) return;
  atomicAdd(&cnt[ei[N_EDGES + e]], 1);
}

#define VPT 8
__global__ __launch_bounds__(1024) void scan_kernel(
    const int* __restrict__ cnt, int* __restrict__ row) {
  __shared__ int wsum[16];
  __shared__ int scarry;
  int t = threadIdx.x;
  int lane = t & 63, wid = t >> 6;
  if (t == 0) scarry = 0;
  __syncthreads();
  for (int base = 0; base < N_NODES; base += 1024 * VPT) {
    int v[VPT];
    int idx0 = base + t * VPT;
    #pragma unroll
    for (int i = 0; i < VPT; ++i) {
      int idx = idx0 + i;
      v[i] = (idx < N_NODES) ? cnt[idx] : 0;
    }
    #pragma unroll
    for (int i = 1; i < VPT; ++i) v[i] += v[i - 1];
    int tsum = v[VPT - 1];
    int s = tsum;
    #pragma unroll
    for (int d = 1; d < 64; d <<= 1) {
      int u = __shfl_up(s, d, 64);
      if (lane >= d) s += u;
    }
    if (lane == 63) wsum[wid] = s;
    __syncthreads();
    if (wid == 0) {
      int ws = (lane < 16) ? wsum[lane] : 0;
      #pragma unroll
      for (int d = 1; d < 16; d <<= 1) {
        int u = __shfl_up(ws, d, 64);
        if (lane >= d) ws += u;
      }
      if (lane < 16) wsum[lane] = ws;
    }
    __syncthreads();
    int wave_excl = (wid == 0) ? 0 : wsum[wid - 1];
    int thread_excl = scarry + wave_excl + (s - tsum);
    if (idx0 < N_NODES) row[idx0] = thread_excl;
    #pragma unroll
    for (int i = 1; i < VPT; ++i) {
      int idx = idx0 + i;
      if (idx < N_NODES) row[idx] = thread_excl + v[i - 1];
    }
    __syncthreads();
    if (t == 0) scarry += wsum[15];
    __syncthreads();
  }
  if (t == 0) row[N_NODES] = scarry;
}

__global__ __launch_bounds__(256) void scatter_kernel(
    const int* __restrict__ ei, const int* __restrict__ row,
    int* __restrict__ fill, int* __restrict__ srt_src) {
  int e = blockIdx.x * 256 + threadIdx.x;
  if (e >= N_EDGES) return;
  int s = ei[e];
  int d = ei[N_EDGES + e];
  int pos = row[d] + atomicAdd(&fill[d], 1);
  srt_src[pos] = s;
}

// ---------------------------------------------------------------- CSR aggregation
__global__ __launch_bounds__(256) void agg_csr_kernel(
    const float* __restrict__ x, const int* __restrict__ row,
    const int* __restrict__ srt, float* __restrict__ agg) {
  int n = blockIdx.x * 8 + (threadIdx.x >> 5);
  int c = threadIdx.x & 31;
  int lo = row[n], hi = row[n + 1];
  const float4* x4 = (const float4*)x;
  float4 acc = make_float4(0.f, 0.f, 0.f, 0.f);
  int k = lo;
  for (; k + 2 <= hi; k += 2) {
    int s0 = srt[k], s1 = srt[k + 1];
    float4 a = x4[(size_t)s0 * 32 + c];
    float4 b = x4[(size_t)s1 * 32 + c];
    acc.x += a.x + b.x; acc.y += a.y + b.y;
    acc.z += a.z + b.z; acc.w += a.w + b.w;
  }
  if (k < hi) {
    float4 a = x4[(size_t)srt[k] * 32 + c];
    acc.x += a.x; acc.y += a.y; acc.z += a.z; acc.w += a.w;
  }
  ((float4*)agg)[(size_t)n * 32 + c] = acc;
}

// ---------------------------------------------------------------- MFMA MLP
// OUT = relu( Wb · relu(Wa · (xin+agg)^T + ba) + bb )^T, bf16 inputs f32 accum.
// Block: 256 thr = 4 waves; 64 nodes/block; wave w owns j in [32w, 32w+32).
// X/H in LDS bf16 [64][128], 16B-chunk XOR swizzle (chunk ^= row&7).
__global__ __launch_bounds__(256) void mlp_mfma_kernel(
    const float* __restrict__ xin, const float* __restrict__ agg,
    const float* __restrict__ wa, const float* __restrict__ ba,
    const float* __restrict__ wb, const float* __restrict__ bb,
    float* __restrict__ xout) {
  __shared__ short Xs[64 * 128];   // 16 KB
  __shared__ short Hs[64 * 128];   // 16 KB
  int t = threadIdx.x;
  int lane = t & 63;
  int w = t >> 6;
  int jq = w * 32;
  int l15 = lane & 15;
  int lg = lane >> 4;              // 0..3
  int nbase = blockIdx.x * 64;

  // A-operand fragments of Wa, Wb (lane l: W[jrow][ks*32 + lg*8 + e])
  bf16x8 waf[2][4], wbf[2][4];
  #pragma unroll
  for (int jm = 0; jm < 2; ++jm) {
    int jrow = jq + jm * 16 + l15;
    #pragma unroll
    for (int ks = 0; ks < 4; ++ks) {
      int k0 = ks * 32 + lg * 8;
      f32x4 a0 = *(const f32x4*)(wa + jrow * DIM + k0);
      f32x4 a1 = *(const f32x4*)(wa + jrow * DIM + k0 + 4);
      f32x4 c0 = *(const f32x4*)(wb + jrow * DIM + k0);
      f32x4 c1 = *(const f32x4*)(wb + jrow * DIM + k0 + 4);
      bf16x8 fa, fb;
      #pragma unroll
      for (int e = 0; e < 4; ++e) {
        fa[e] = (short)f2bf(a0[e]); fa[4 + e] = (short)f2bf(a1[e]);
        fb[e] = (short)f2bf(c0[e]); fb[4 + e] = (short)f2bf(c1[e]);
      }
      waf[jm][ks] = fa; wbf[jm][ks] = fb;
    }
  }
  f32x4 ba_r[2], bb_r[2];
  #pragma unroll
  for (int jm = 0; jm < 2; ++jm) {
    ba_r[jm] = *(const f32x4*)(ba + jq + jm * 16 + lg * 4);
    bb_r[jm] = *(const f32x4*)(bb + jq + jm * 16 + lg * 4);
  }

  // stage X = bf16(xin + agg), swizzled
  {
    int r = t >> 2;
    int cb = (t & 3) * 4;
    int node = nbase + r;
    #pragma unroll
    for (int i = 0; i < 4; ++i) {
      int chunk = cb + i;
      bf16x8 v = {0, 0, 0, 0, 0, 0, 0, 0};
      if (node < N_NODES) {
        const f32x4* xp = (const f32x4*)(xin + (size_t)node * DIM + chunk * 8);
        const f32x4* ap = (const f32x4*)(agg + (size_t)node * DIM + chunk * 8);
        f32x4 x0 = xp[0], x1 = xp[1], g0 = ap[0], g1 = ap[1];
        #pragma unroll
        for (int e = 0; e < 4; ++e) {
          v[e] = (short)f2bf(x0[e] + g0[e]);
          v[4 + e] = (short)f2bf(x1[e] + g1[e]);
        }
      }
      *(bf16x8*)&Xs[r * 128 + ((chunk ^ (r & 7)) << 3)] = v;
    }
  }
  __syncthreads();

  // GEMM1: H^T tiles; D col = node, row = j
  #pragma unroll
  for (int nt = 0; nt < 4; ++nt) {
    int row = nt * 16 + l15;
    bf16x8 xf[4];
    #pragma unroll
    for (int ks = 0; ks < 4; ++ks) {
      int chunk = ks * 4 + lg;
      xf[ks] = *(const bf16x8*)&Xs[row * 128 + ((chunk ^ (row & 7)) << 3)];
    }
    #pragma unroll
    for (int jm = 0; jm < 2; ++jm) {
      f32x4 acc = ba_r[jm];
      #pragma unroll
      for (int ks = 0; ks < 4; ++ks)
        acc = __builtin_amdgcn_mfma_f32_16x16x32_bf16(waf[jm][ks], xf[ks], acc, 0, 0, 0);
      int hnode = nt * 16 + l15;
      int cbase = jq + jm * 16 + lg * 4;
      unsigned p0 = (unsigned)f2bf(fmaxf(acc[0], 0.f)) |
                    ((unsigned)f2bf(fmaxf(acc[1], 0.f)) << 16);
      unsigned p1 = (unsigned)f2bf(fmaxf(acc[2], 0.f)) |
                    ((unsigned)f2bf(fmaxf(acc[3], 0.f)) << 16);
      unsigned idx = hnode * 128 + (((cbase >> 3) ^ (hnode & 7)) << 3) + (cbase & 7);
      *(uint2*)&Hs[idx] = make_uint2(p0, p1);
    }
  }
  __syncthreads();

  // GEMM2: OUT tiles; store relu as float4
  #pragma unroll
  for (int nt = 0; nt < 4; ++nt) {
    int row = nt * 16 + l15;
    bf16x8 hf[4];
    #pragma unroll
    for (int ks = 0; ks < 4; ++ks) {
      int chunk = ks * 4 + lg;
      hf[ks] = *(const bf16x8*)&Hs[row * 128 + ((chunk ^ (row & 7)) << 3)];
    }
    #pragma unroll
    for (int jm = 0; jm < 2; ++jm) {
      f32x4 acc = bb_r[jm];
      #pragma unroll
      for (int ks = 0; ks < 4; ++ks)
        acc = __builtin_amdgcn_mfma_f32_16x16x32_bf16(wbf[jm][ks], hf[ks], acc, 0, 0, 0);
      int node = nbase + nt * 16 + l15;
      if (node < N_NODES) {
        f32x4 r;
        #pragma unroll
        for (int e = 0; e < 4; ++e) r[e] = fmaxf(acc[e], 0.f);
        *(f32x4*)(xout + (size_t)node * DIM + jq + jm * 16 + lg * 4) = r;
      }
    }
  }
}

// ---------------------------------------------------------------- mean-pool + FC
__global__ __launch_bounds__(128) void pool_fc_kernel(
    const float* __restrict__ x, const int* __restrict__ batch,
    const float* __restrict__ fcw, const float* __restrict__ fcb,
    float* __restrict__ out) {
  int g = blockIdx.x, t = threadIdx.x;
  __shared__ float pooled[DIM];
  __shared__ int sbound[2];
  if (t < 2) {
    int target = g + t;
    int lo = 0, hi = N_NODES;
    while (lo < hi) {
      int m = (lo + hi) >> 1;
      if (batch[m] < target) lo = m + 1; else hi = m;
    }
    sbound[t] = lo;
  }
  __syncthreads();
  int lo = sbound[0], hi = sbound[1];
  float s = 0.f;
  for (int nn = lo; nn < hi; ++nn) s += x[(size_t)nn * DIM + t];
  pooled[t] = s / fmaxf((float)(hi - lo), 1.0f);
  __syncthreads();
  if (t < ODIM) {
    float a = fcb[t];
    const float* wr = fcw + (size_t)t * DIM;
    #pragma unroll 8
    for (int h = 0; h < DIM; ++h) a += pooled[h] * wr[h];
    out[(size_t)g * ODIM + t] = a;
  }
}

// ---------------------------------------------------------------- launch
extern "C" void kernel_launch(void* const* d_in, const int* in_sizes, int n_in,
                              void* d_out, int out_size, void* d_ws, size_t ws_size,
                              hipStream_t stream) {
  const float* emb  = (const float*)d_in[0];
  const float* w1a  = (const float*)d_in[1];
  const float* b1a  = (const float*)d_in[2];
  const float* w1b  = (const float*)d_in[3];
  const float* b1b  = (const float*)d_in[4];
  const float* w2a  = (const float*)d_in[5];
  const float* b2a  = (const float*)d_in[6];
  const float* w2b  = (const float*)d_in[7];
  const float* b2b  = (const float*)d_in[8];
  const float* fcw  = (const float*)d_in[9];
  const float* fcb  = (const float*)d_in[10];
  const int*   xidx = (const int*)d_in[11];
  const int*   ei   = (const int*)d_in[12];
  const int*   batch= (const int*)d_in[13];
  float* out = (float*)d_out;

  size_t feat_bytes = (size_t)N_NODES * DIM * sizeof(float);
  char* ws = (char*)d_ws;
  float* A = (float*)ws;
  float* B = (float*)(ws + feat_bytes);
  float* C = (float*)(ws + 2 * feat_bytes);
  char*  p = ws + 3 * feat_bytes;
  int* row = (int*)p;                p += ((N_NODES + 1) * 4 + 15) / 16 * 16;
  int* cnt = (int*)p;                p += (N_NODES * 4 + 15) / 16 * 16;
  int* srt = (int*)p;

  embed_kernel<<<(N_NODES * 32 + 255) / 256, 256, 0, stream>>>(emb, xidx, A);

  hipMemsetAsync(cnt, 0, N_NODES * sizeof(int), stream);
  hist_kernel<<<N_EDGES / 256, 256, 0, stream>>>(ei, cnt);
  scan_kernel<<<1, 1024, 0, stream>>>(cnt, row);
  hipMemsetAsync(cnt, 0, N_NODES * sizeof(int), stream);
  scatter_kernel<<<N_EDGES / 256, 256, 0, stream>>>(ei, row, cnt, srt);

  agg_csr_kernel<<<N_NODES / 8, 256, 0, stream>>>(A, row, srt, B);
  mlp_mfma_kernel<<<(N_NODES + 63) / 64, 256, 0, stream>>>(A, B, w1a, b1a, w1b, b1b, C);

  agg_csr_kernel<<<N_NODES / 8, 256, 0, stream>>>(C, row, srt, B);
  mlp_mfma_kernel<<<(N_NODES + 63) / 64, 256, 0, stream>>>(C, B, w2a, b2a, w2b, b2b, A);

  pool_fc_kernel<<<NGRAPH, 128, 0, stream>>>(A, batch, fcw, fcb, out);
}